// Round 9
// baseline (278.015 us; speedup 1.0000x reference)
//
#include <hip/hip_runtime.h>
#include <stdint.h>

// ---------------------------------------------------------------------------
// HistoryEmbTable: emb.at[push_idx].set(x) then gather emb[pull_idx].
// Last push (highest i) wins on duplicate push indices.
//
// Partition pipeline:
//   bucket = key>>17 (512 buckets, 512KB emb window each)
//   K1/K2: LDS-staged 512-bin scatter of (key,pos)/(key,j); LDS-atomic
//          ranking, bin-contiguous copy-out, ~512 global cursor atomics/block.
//   K3:    per-bucket exact last-write-wins hash in LDS (16K x u64 = 128KB).
//          Round-8: block=big (128KB table -> 1 WG/CU; waves must come from
//          block size) -> 244us total. Round-9: match was latency-CHAIN
//          bound (1 dependent emb-load->LDS-probe->store per thread-iter
//          ~= 107us model == measured). Fix: MBLK=512 (VGPR cap 128) with
//          8-way independent batching in the probe phase: int4x2 key load,
//          8 emb + 8 probe loads in flight, resolve, float4x2 store.
//   K4:    out[j] = staging[dest[j]].
// Winner = max push pos (order-free); each j reads its own staging slot, so
// output is deterministic despite nondeterministic scatter order.
// ---------------------------------------------------------------------------

typedef unsigned long long u64;
typedef unsigned u32;

#define NB     512              // buckets
#define BSHIFT 17               // bucket = key >> 17 (keys < 2^26)
#define BLK    256
#define MBLK   512              // match block: 8 waves, VGPR cap 128
#define MB     8                // match batch (items/thread/iter)
#define VPT    16
#define CHUNK  (BLK * VPT)      // 4096 items per scatter block
#define CAP    12288            // per-bucket run capacity (mean 8734, +38 sigma)
#define CPAD   16               // ints per cursor (64B line)
#define LSLOTS 16384            // LDS hash slots (128KB)
#define LMASK  (LSLOTS - 1)

__device__ __forceinline__ u32 hkey(int key) { return (u32)key * 2654435761u; }

// ---- K1/K2: LDS-binned scatter into 512 bucket runs ----
template <bool IS_PUSH>
__global__ __launch_bounds__(BLK)
void scatter_kernel(const int* __restrict__ idx, int n,
                    int* __restrict__ cursors,      // [NB*CPAD]
                    u64* __restrict__ push_runs,    // [NB*CAP]   (push)
                    int* __restrict__ pull_keys,    // [NB*CAP]   (pull)
                    int* __restrict__ dest) {       // [n]        (pull)
    __shared__ u64 buf[CHUNK];          // 32KB
    __shared__ int cnt[NB];             // 2KB
    __shared__ int basel[NB];           // 2KB
    __shared__ int baseg[NB];           // 2KB
    __shared__ int scan[NB];            // 2KB
    int t = threadIdx.x;
    for (int b = t; b < NB; b += BLK) cnt[b] = 0;
    __syncthreads();

    int base = blockIdx.x * CHUNK;
    int   key_r[VPT];
    short bin_r[VPT];                   // < 512
    short pos_r[VPT];                   // < 4096
    #pragma unroll
    for (int e = 0; e < VPT; ++e) {
        int i = base + e * BLK + t;     // coalesced index load
        if (i < n) {
            int key = idx[i];
            int b = key >> BSHIFT;
            key_r[e] = key;
            bin_r[e] = (short)b;
            pos_r[e] = (short)atomicAdd(&cnt[b], 1);   // LDS atomic (cheap)
        } else bin_r[e] = -1;
    }
    __syncthreads();

    // exclusive scan of cnt -> basel (Hillis-Steele, 2 elems/thread)
    scan[t] = cnt[t]; scan[t + BLK] = cnt[t + BLK];
    __syncthreads();
    for (int d = 1; d < NB; d <<= 1) {
        int a0 = (t       >= d) ? scan[t       - d] : 0;
        int a1 = (t + BLK >= d) ? scan[t + BLK - d] : 0;
        __syncthreads();
        scan[t] += a0; scan[t + BLK] += a1;
        __syncthreads();
    }
    basel[t]       = scan[t]       - cnt[t];
    basel[t + BLK] = scan[t + BLK] - cnt[t + BLK];
    __syncthreads();

    // reserve global run space: ~512 global atomics per block (not 4096)
    for (int b = t; b < NB; b += BLK)
        if (cnt[b] > 0) baseg[b] = atomicAdd(&cursors[b * CPAD], cnt[b]);

    // stage items into LDS, bin-grouped
    #pragma unroll
    for (int e = 0; e < VPT; ++e) {
        if (bin_r[e] >= 0) {
            int i = base + e * BLK + t;
            buf[basel[bin_r[e]] + pos_r[e]] =
                ((u64)(u32)key_r[e] << 32) | (u32)i;    // key | original index
        }
    }
    __syncthreads();

    // copy out: consecutive threads -> consecutive buf slots -> bin-contiguous
    int total = scan[NB - 1];
    for (int q = t; q < total; q += BLK) {
        u64 packed = buf[q];
        int key = (int)(packed >> 32);
        int b = key >> BSHIFT;
        int r = baseg[b] + (q - basel[b]);
        if (r < CAP) {                                  // overflow guard (P~0)
            int gp = b * CAP + r;
            if (IS_PUSH) {
                push_runs[gp] = packed;                 // key | push pos
            } else {
                pull_keys[gp] = key;
                dest[(u32)packed] = gp;                 // dest[j] = staging slot
            }
        }
    }
}

// ---- K3: per-bucket LDS-exact match + window-local emb gather ----
__global__ __launch_bounds__(MBLK)
void match_kernel(const u64* __restrict__ push_runs,
                  const int* __restrict__ pull_keys,
                  const int* __restrict__ cur_push,
                  const int* __restrict__ cur_pull,
                  const float* __restrict__ x,
                  const float* __restrict__ emb,
                  float* __restrict__ staging) {
    __shared__ u64 tbl[LSLOTS];   // 128KB -> 1 WG/CU; waves come from MBLK
    int b = blockIdx.x;
    int np = cur_push[b * CPAD]; np = np < CAP ? np : CAP;
    int nl = cur_pull[b * CPAD]; nl = nl < CAP ? nl : CAP;
    for (int i = threadIdx.x; i < LSLOTS; i += MBLK) tbl[i] = 0ull;
    __syncthreads();

    // build exact last-write-wins hash of this bucket's pushes (LDS atomics)
    const u64* prun = push_runs + (size_t)b * CAP;
    for (int i = threadIdx.x; i < np; i += MBLK) {
        u64 packed = prun[i];
        u32 key1 = (u32)(packed >> 32) + 1u;
        u64 want = ((u64)key1 << 32) | ((u32)packed + 1u);   // (key+1)|(pos+1)
        u32 s = (hkey((int)(packed >> 32)) >> 18) & LMASK;
        for (;;) {
            u64 prev = atomicCAS(&tbl[s], 0ull, want);
            if (prev == 0ull) break;                          // claimed
            if ((prev >> 32) == key1) { atomicMax(&tbl[s], want); break; }
            s = (s + 1) & LMASK;
        }
    }
    __syncthreads();

    // probe pulls, 8-way batched: 8 emb loads + 8 LDS probes in flight/thread
    const int* lkeys = pull_keys + (size_t)b * CAP;
    float* stg = staging + (size_t)b * CAP;
    const int STRIDE = MBLK * MB;                 // 4096
    for (int i = threadIdx.x * MB; i + MB <= nl; i += STRIDE) {
        int4 a0 = *(const int4*)(lkeys + i);
        int4 a1 = *(const int4*)(lkeys + i + 4);
        int k[MB] = {a0.x, a0.y, a0.z, a0.w, a1.x, a1.y, a1.z, a1.w};
        float g[MB];
        #pragma unroll
        for (int e = 0; e < MB; ++e) g[e] = emb[k[e]];        // 8 in flight
        u32 s[MB]; u64 tv[MB];
        #pragma unroll
        for (int e = 0; e < MB; ++e) s[e] = (hkey(k[e]) >> 18) & LMASK;
        #pragma unroll
        for (int e = 0; e < MB; ++e) tv[e] = tbl[s[e]];       // 8 in flight
        float r[MB];
        #pragma unroll
        for (int e = 0; e < MB; ++e) {
            u64 cur = tv[e]; u32 slot = s[e]; float v = g[e];
            u32 key1 = (u32)k[e] + 1u;
            while (cur != 0ull) {
                if ((cur >> 32) == key1) { v = x[(u32)cur - 1u]; break; }
                slot = (slot + 1) & LMASK;
                cur = tbl[slot];
            }
            r[e] = v;
        }
        *(float4*)(stg + i)     = make_float4(r[0], r[1], r[2], r[3]);
        *(float4*)(stg + i + 4) = make_float4(r[4], r[5], r[6], r[7]);
    }
    // tail (< MB items)
    int tail = nl & ~(MB - 1);
    for (int i = tail + threadIdx.x; i < nl; i += MBLK) {
        int key = lkeys[i];
        float v = emb[key];
        u32 key1 = (u32)key + 1u;
        u32 s = (hkey(key) >> 18) & LMASK;
        for (;;) {
            u64 cur = tbl[s];
            if (cur == 0ull) break;
            if ((cur >> 32) == key1) { v = x[(u32)cur - 1u]; break; }
            s = (s + 1) & LMASK;
        }
        stg[i] = v;
    }
}

// ---- K4: unpermute ----
__global__ __launch_bounds__(BLK)
void unpermute_kernel(const int* __restrict__ dest,
                      const float* __restrict__ staging,
                      float* __restrict__ out, int n) {
    int j0 = (blockIdx.x * BLK + threadIdx.x) * 4;
    if (j0 + 4 <= n) {
        int4 d = *(const int4*)(dest + j0);
        *(float4*)(out + j0) =
            make_float4(staging[d.x], staging[d.y], staging[d.z], staging[d.w]);
    } else {
        for (int j = j0; j < n; ++j) out[j] = staging[dest[j]];
    }
}

extern "C" void kernel_launch(void* const* d_in, const int* in_sizes, int n_in,
                              void* d_out, int out_size, void* d_ws, size_t ws_size,
                              hipStream_t stream) {
    const float* emb      = (const float*)d_in[0];
    const float* x        = (const float*)d_in[1];
    const int*   push_idx = (const int*)d_in[2];
    const int*   pull_idx = (const int*)d_in[3];
    float* out = (float*)d_out;

    const int n_push = in_sizes[2];
    const int n_pull = in_sizes[3];

    // ws layout: [cur_push][cur_pull] (zeroed) [push_runs][pull_keys][staging][dest]
    char* p = (char*)d_ws;
    int* cur_push = (int*)p;                  p += (size_t)NB * CPAD * 4;
    int* cur_pull = (int*)p;                  p += (size_t)NB * CPAD * 4;
    size_t zero_bytes = (size_t)(p - (char*)d_ws);
    u64*   push_runs = (u64*)p;               p += (size_t)NB * CAP * 8;
    int*   pull_keys = (int*)p;               p += (size_t)NB * CAP * 4;
    float* staging   = (float*)p;             p += (size_t)NB * CAP * 4;
    int*   dest      = (int*)p;               p += (size_t)n_pull * 4;

    hipMemsetAsync(d_ws, 0, zero_bytes, stream);   // 64KB only

    int grid_push = (n_push + CHUNK - 1) / CHUNK;
    int grid_pull = (n_pull + CHUNK - 1) / CHUNK;
    scatter_kernel<true><<<grid_push, BLK, 0, stream>>>(
        push_idx, n_push, cur_push, push_runs, nullptr, nullptr);
    scatter_kernel<false><<<grid_pull, BLK, 0, stream>>>(
        pull_idx, n_pull, cur_pull, nullptr, pull_keys, dest);
    match_kernel<<<NB, MBLK, 0, stream>>>(push_runs, pull_keys,
                                          cur_push, cur_pull, x, emb, staging);
    unpermute_kernel<<<(n_pull + BLK * 4 - 1) / (BLK * 4), BLK, 0, stream>>>(
        dest, staging, out, n_pull);
}

// Round 10
// 239.865 us; speedup vs baseline: 1.1590x; 1.1590x over previous
//
#include <hip/hip_runtime.h>
#include <stdint.h>

// ---------------------------------------------------------------------------
// HistoryEmbTable: emb.at[push_idx].set(x) then gather emb[pull_idx].
// Last push (highest i) wins on duplicate push indices.
//
// Partition pipeline:
//   bucket = key>>17 (512 buckets, 512KB emb window each)
//   K1/K2: LDS-staged 512-bin scatter of (key,pos)/(key,j); LDS-atomic
//          ranking, bin-contiguous copy-out, ~512 global cursor atomics/block.
//   K3:    per-bucket exact last-write-wins hash in LDS (16K x u64 = 128KB),
//          MBLK=1024 (16 waves/CU; the 128KB table forces 1 WG/CU so waves
//          must come from block size — round-8 lesson; round-9 showed that
//          trading waves for per-thread batch REGRESSES because the cost is
//          the DEPENDENT LDS probe walk at lf 0.53, ~2.8 reads x 120cy for
//          the 93.5% not-pushed majority).
//          Round-10: 16KB LDS bloom bitmap (2^17 bits) of pushed keys kills
//          the walk for ~87.7% of pulls (FP ~6.2%): 1x4B LDS read instead of
//          ~2.8x8B dependent reads. emb[key] issued first (chain-break),
//          batch-4 with int4 key load / float4 staging store.
//   K4:    out[j] = staging[dest[j]].
// Winner = max push pos (order-free); each j reads its own staging slot, so
// output is deterministic despite nondeterministic scatter order.
// ---------------------------------------------------------------------------

typedef unsigned long long u64;
typedef unsigned u32;

#define NB     512              // buckets
#define BSHIFT 17               // bucket = key >> 17 (keys < 2^26)
#define BLK    256
#define MBLK   1024             // match block: 16 waves
#define MB     4                // match batch (items/thread/iter)
#define VPT    16
#define CHUNK  (BLK * VPT)      // 4096 items per scatter block
#define CAP    12288            // per-bucket run capacity (mean 8734, +38 sigma)
#define CPAD   16               // ints per cursor (64B line)
#define LSLOTS 16384            // LDS hash slots (128KB)
#define LMASK  (LSLOTS - 1)
#define BBITS  131072           // bloom bits (2^17) = 16KB
#define BWORDS (BBITS / 32)
#define BMASK  (BBITS - 1)

__device__ __forceinline__ u32 hkey(int key) { return (u32)key * 2654435761u; }

// ---- K1/K2: LDS-binned scatter into 512 bucket runs ----
template <bool IS_PUSH>
__global__ __launch_bounds__(BLK)
void scatter_kernel(const int* __restrict__ idx, int n,
                    int* __restrict__ cursors,      // [NB*CPAD]
                    u64* __restrict__ push_runs,    // [NB*CAP]   (push)
                    int* __restrict__ pull_keys,    // [NB*CAP]   (pull)
                    int* __restrict__ dest) {       // [n]        (pull)
    __shared__ u64 buf[CHUNK];          // 32KB
    __shared__ int cnt[NB];             // 2KB
    __shared__ int basel[NB];           // 2KB
    __shared__ int baseg[NB];           // 2KB
    __shared__ int scan[NB];            // 2KB
    int t = threadIdx.x;
    for (int b = t; b < NB; b += BLK) cnt[b] = 0;
    __syncthreads();

    int base = blockIdx.x * CHUNK;
    int   key_r[VPT];
    short bin_r[VPT];                   // < 512
    short pos_r[VPT];                   // < 4096
    #pragma unroll
    for (int e = 0; e < VPT; ++e) {
        int i = base + e * BLK + t;     // coalesced index load
        if (i < n) {
            int key = idx[i];
            int b = key >> BSHIFT;
            key_r[e] = key;
            bin_r[e] = (short)b;
            pos_r[e] = (short)atomicAdd(&cnt[b], 1);   // LDS atomic (cheap)
        } else bin_r[e] = -1;
    }
    __syncthreads();

    // exclusive scan of cnt -> basel (Hillis-Steele, 2 elems/thread)
    scan[t] = cnt[t]; scan[t + BLK] = cnt[t + BLK];
    __syncthreads();
    for (int d = 1; d < NB; d <<= 1) {
        int a0 = (t       >= d) ? scan[t       - d] : 0;
        int a1 = (t + BLK >= d) ? scan[t + BLK - d] : 0;
        __syncthreads();
        scan[t] += a0; scan[t + BLK] += a1;
        __syncthreads();
    }
    basel[t]       = scan[t]       - cnt[t];
    basel[t + BLK] = scan[t + BLK] - cnt[t + BLK];
    __syncthreads();

    // reserve global run space: ~512 global atomics per block (not 4096)
    for (int b = t; b < NB; b += BLK)
        if (cnt[b] > 0) baseg[b] = atomicAdd(&cursors[b * CPAD], cnt[b]);

    // stage items into LDS, bin-grouped
    #pragma unroll
    for (int e = 0; e < VPT; ++e) {
        if (bin_r[e] >= 0) {
            int i = base + e * BLK + t;
            buf[basel[bin_r[e]] + pos_r[e]] =
                ((u64)(u32)key_r[e] << 32) | (u32)i;    // key | original index
        }
    }
    __syncthreads();

    // copy out: consecutive threads -> consecutive buf slots -> bin-contiguous
    int total = scan[NB - 1];
    for (int q = t; q < total; q += BLK) {
        u64 packed = buf[q];
        int key = (int)(packed >> 32);
        int b = key >> BSHIFT;
        int r = baseg[b] + (q - basel[b]);
        if (r < CAP) {                                  // overflow guard (P~0)
            int gp = b * CAP + r;
            if (IS_PUSH) {
                push_runs[gp] = packed;                 // key | push pos
            } else {
                pull_keys[gp] = key;
                dest[(u32)packed] = gp;                 // dest[j] = staging slot
            }
        }
    }
}

// ---- K3: per-bucket LDS-exact match (+bloom) + window-local emb gather ----
__global__ __launch_bounds__(MBLK)
void match_kernel(const u64* __restrict__ push_runs,
                  const int* __restrict__ pull_keys,
                  const int* __restrict__ cur_push,
                  const int* __restrict__ cur_pull,
                  const float* __restrict__ x,
                  const float* __restrict__ emb,
                  float* __restrict__ staging) {
    __shared__ u64 tbl[LSLOTS];     // 128KB
    __shared__ u32 bloom[BWORDS];   // 16KB  (total 144KB -> still 1 WG/CU)
    int b = blockIdx.x;
    int np = cur_push[b * CPAD]; np = np < CAP ? np : CAP;
    int nl = cur_pull[b * CPAD]; nl = nl < CAP ? nl : CAP;
    for (int i = threadIdx.x; i < LSLOTS; i += MBLK) tbl[i] = 0ull;
    for (int i = threadIdx.x; i < BWORDS; i += MBLK) bloom[i] = 0u;
    __syncthreads();

    // build: bloom bit + exact last-write-wins hash (LDS atomics)
    const u64* prun = push_runs + (size_t)b * CAP;
    for (int i = threadIdx.x; i < np; i += MBLK) {
        u64 packed = prun[i];
        int key = (int)(packed >> 32);
        u32 h = hkey(key);
        atomicOr(&bloom[(h & BMASK) >> 5], 1u << (h & 31));
        u32 key1 = (u32)key + 1u;
        u64 want = ((u64)key1 << 32) | ((u32)packed + 1u);   // (key+1)|(pos+1)
        u32 s = (h >> 18) & LMASK;
        for (;;) {
            u64 prev = atomicCAS(&tbl[s], 0ull, want);
            if (prev == 0ull) break;                          // claimed
            if ((prev >> 32) == key1) { atomicMax(&tbl[s], want); break; }
            s = (s + 1) & LMASK;
        }
    }
    __syncthreads();

    // probe pulls, batch-4: emb loads in flight; bloom kills the walk for
    // ~87.7% of pulls (not-pushed 93.5% x (1 - FP 6.2%)).
    const int* lkeys = pull_keys + (size_t)b * CAP;
    float* stg = staging + (size_t)b * CAP;
    const int STRIDE = MBLK * MB;                 // 4096
    for (int i = threadIdx.x * MB; i + MB <= nl; i += STRIDE) {
        int4 kk = *(const int4*)(lkeys + i);
        int k[MB] = {kk.x, kk.y, kk.z, kk.w};
        float g[MB];
        #pragma unroll
        for (int e = 0; e < MB; ++e) g[e] = emb[k[e]];        // 4 in flight
        u32 h[MB], bw[MB];
        #pragma unroll
        for (int e = 0; e < MB; ++e) h[e] = hkey(k[e]);
        #pragma unroll
        for (int e = 0; e < MB; ++e) bw[e] = bloom[(h[e] & BMASK) >> 5];
        float r[MB];
        #pragma unroll
        for (int e = 0; e < MB; ++e) {
            float v = g[e];
            if ((bw[e] >> (h[e] & 31)) & 1u) {                // maybe pushed
                u32 key1 = (u32)k[e] + 1u;
                u32 s = (h[e] >> 18) & LMASK;
                for (;;) {
                    u64 cur = tbl[s];
                    if (cur == 0ull) break;                   // bloom FP
                    if ((cur >> 32) == key1) { v = x[(u32)cur - 1u]; break; }
                    s = (s + 1) & LMASK;
                }
            }
            r[e] = v;
        }
        *(float4*)(stg + i) = make_float4(r[0], r[1], r[2], r[3]);
    }
    // tail (< MB items at the end)
    int tail = (nl / MB) * MB;
    for (int i = tail + threadIdx.x; i < nl; i += MBLK) {
        int key = lkeys[i];
        float v = emb[key];
        u32 h = hkey(key);
        if ((bloom[(h & BMASK) >> 5] >> (h & 31)) & 1u) {
            u32 key1 = (u32)key + 1u;
            u32 s = (h >> 18) & LMASK;
            for (;;) {
                u64 cur = tbl[s];
                if (cur == 0ull) break;
                if ((cur >> 32) == key1) { v = x[(u32)cur - 1u]; break; }
                s = (s + 1) & LMASK;
            }
        }
        stg[i] = v;
    }
}

// ---- K4: unpermute ----
__global__ __launch_bounds__(BLK)
void unpermute_kernel(const int* __restrict__ dest,
                      const float* __restrict__ staging,
                      float* __restrict__ out, int n) {
    int j0 = (blockIdx.x * BLK + threadIdx.x) * 4;
    if (j0 + 4 <= n) {
        int4 d = *(const int4*)(dest + j0);
        *(float4*)(out + j0) =
            make_float4(staging[d.x], staging[d.y], staging[d.z], staging[d.w]);
    } else {
        for (int j = j0; j < n; ++j) out[j] = staging[dest[j]];
    }
}

extern "C" void kernel_launch(void* const* d_in, const int* in_sizes, int n_in,
                              void* d_out, int out_size, void* d_ws, size_t ws_size,
                              hipStream_t stream) {
    const float* emb      = (const float*)d_in[0];
    const float* x        = (const float*)d_in[1];
    const int*   push_idx = (const int*)d_in[2];
    const int*   pull_idx = (const int*)d_in[3];
    float* out = (float*)d_out;

    const int n_push = in_sizes[2];
    const int n_pull = in_sizes[3];

    // ws layout: [cur_push][cur_pull] (zeroed) [push_runs][pull_keys][staging][dest]
    char* p = (char*)d_ws;
    int* cur_push = (int*)p;                  p += (size_t)NB * CPAD * 4;
    int* cur_pull = (int*)p;                  p += (size_t)NB * CPAD * 4;
    size_t zero_bytes = (size_t)(p - (char*)d_ws);
    u64*   push_runs = (u64*)p;               p += (size_t)NB * CAP * 8;
    int*   pull_keys = (int*)p;               p += (size_t)NB * CAP * 4;
    float* staging   = (float*)p;             p += (size_t)NB * CAP * 4;
    int*   dest      = (int*)p;               p += (size_t)n_pull * 4;

    hipMemsetAsync(d_ws, 0, zero_bytes, stream);   // 64KB only

    int grid_push = (n_push + CHUNK - 1) / CHUNK;
    int grid_pull = (n_pull + CHUNK - 1) / CHUNK;
    scatter_kernel<true><<<grid_push, BLK, 0, stream>>>(
        push_idx, n_push, cur_push, push_runs, nullptr, nullptr);
    scatter_kernel<false><<<grid_pull, BLK, 0, stream>>>(
        pull_idx, n_pull, cur_pull, nullptr, pull_keys, dest);
    match_kernel<<<NB, MBLK, 0, stream>>>(push_runs, pull_keys,
                                          cur_push, cur_pull, x, emb, staging);
    unpermute_kernel<<<(n_pull + BLK * 4 - 1) / (BLK * 4), BLK, 0, stream>>>(
        dest, staging, out, n_pull);
}